// Round 11
// baseline (2590.220 us; speedup 1.0000x reference)
//
#include <hip/hip_runtime.h>
#include <math.h>

#define NN 3072
#define EPSG 1e-20f
#define EDGE_CAP 53248          // ~47.2K expected edges + 28σ margin
typedef unsigned long long u64;

// ---------- prep 1: rowsum0[i] = sum_c adj[i][c] ----------
__global__ __launch_bounds__(256) void rowsum_kernel(const float* __restrict__ adj,
                                                     float* __restrict__ rowsum) {
    int row = blockIdx.x;
    const float* r = adj + (size_t)row * NN;
    float s = 0.f;
    for (int c = threadIdx.x; c < NN; c += 256) s += r[c];
#pragma unroll
    for (int off = 32; off > 0; off >>= 1) s += __shfl_down(s, off);
    __shared__ float ps[4];
    if ((threadIdx.x & 63) == 0) ps[threadIdx.x >> 6] = s;
    __syncthreads();
    if (threadIdx.x == 0) rowsum[row] = (ps[0] + ps[1]) + (ps[2] + ps[3]);
}

// ---------- prep 2: column counts (coalesced: consecutive threads = consecutive c) ----------
__global__ __launch_bounds__(256) void colcnt_kernel(const float* __restrict__ adj,
                                                     unsigned* __restrict__ colcnt) {
    int c = blockIdx.x * 256 + threadIdx.x;
    unsigned cnt = 0;
    for (int i = 0; i < NN; ++i)
        cnt += (adj[(size_t)i * NN + c] != 0.0f) ? 1u : 0u;
    colcnt[c] = cnt;
}

// ---------- prep 3: exclusive prefix sum of column counts (1 wave) ----------
__global__ __launch_bounds__(64) void scan_kernel(const unsigned* __restrict__ colcnt,
                                                  unsigned* __restrict__ eoff) {
    int lane = threadIdx.x;
    unsigned tot = 0;
    for (int k = 0; k < 48; ++k) tot += colcnt[lane * 48 + k];
    unsigned x = tot;
    for (int off = 1; off < 64; off <<= 1) {
        unsigned y = __shfl_up(x, off);
        if (lane >= off) x += y;
    }
    unsigned run = x - tot;                  // exclusive prefix
    for (int k = 0; k < 48; ++k) {
        unsigned c = colcnt[lane * 48 + k];
        eoff[lane * 48 + k] = run;
        run += c;
    }
    if (lane == 63) eoff[NN] = run;
}

// ---------- prep 4: fill CSC edge lists (rows of each column, ascending) ----------
__global__ __launch_bounds__(256) void fill_kernel(const float* __restrict__ adj,
                                                   const unsigned* __restrict__ eoff,
                                                   unsigned short* __restrict__ edges) {
    int c = blockIdx.x * 256 + threadIdx.x;
    unsigned off = eoff[c];
    for (int i = 0; i < NN; ++i) {
        if (adj[(size_t)i * NN + c] != 0.0f) {
            if (off < EDGE_CAP) edges[off] = (unsigned short)i;
            ++off;
        }
    }
}

// monotonic order-preserving float->u32 map (never 0 for finite inputs)
__device__ __forceinline__ unsigned enc32(float v) {
    unsigned u = __float_as_uint(v);
    return (u & 0x80000000u) ? ~u : (u | 0x80000000u);
}

// ---------- prep 5: gumbel + derived per-node arrays ----------
__global__ __launch_bounds__(256) void gumbel_kernel(const float* __restrict__ logits,
                                                     const float* __restrict__ unif,
                                                     const float* __restrict__ rowsum,
                                                     float* __restrict__ out,
                                                     float* __restrict__ elog,
                                                     unsigned* __restrict__ keyenc,
                                                     int* __restrict__ indeg) {
    int j = blockIdx.x * 256 + threadIdx.x;
    float lg = logits[j];
    float u  = unif[j];
    float g  = lg + (-logf(-logf(u + EPSG) + EPSG));
    out[NN + j] = g;                 // gumbel_logits output
    elog[j] = expf(lg);
    keyenc[j] = enc32(g);
    indeg[j] = (int)rowsum[j];
}

// DPP wave64 max-reduce: result valid in lane 63
__device__ __forceinline__ unsigned wmax_u32(unsigned v) {
    unsigned t;
    t = (unsigned)__builtin_amdgcn_update_dpp(0, (int)v, 0x111, 0xf, 0xf, true); v = t > v ? t : v;
    t = (unsigned)__builtin_amdgcn_update_dpp(0, (int)v, 0x112, 0xf, 0xf, true); v = t > v ? t : v;
    t = (unsigned)__builtin_amdgcn_update_dpp(0, (int)v, 0x114, 0xf, 0xf, true); v = t > v ? t : v;
    t = (unsigned)__builtin_amdgcn_update_dpp(0, (int)v, 0x118, 0xf, 0xf, true); v = t > v ? t : v;
    t = (unsigned)__builtin_amdgcn_update_dpp(0, (int)v, 0x142, 0xf, 0xf, true); v = t > v ? t : v;
    t = (unsigned)__builtin_amdgcn_update_dpp(0, (int)v, 0x143, 0xf, 0xf, true); v = t > v ? t : v;
    return v;
}
__device__ __forceinline__ float wsum_f32(float v) {
    int t;
    t = __builtin_amdgcn_update_dpp(0, __float_as_int(v), 0x111, 0xf, 0xf, true); v += __int_as_float(t);
    t = __builtin_amdgcn_update_dpp(0, __float_as_int(v), 0x112, 0xf, 0xf, true); v += __int_as_float(t);
    t = __builtin_amdgcn_update_dpp(0, __float_as_int(v), 0x114, 0xf, 0xf, true); v += __int_as_float(t);
    t = __builtin_amdgcn_update_dpp(0, __float_as_int(v), 0x118, 0xf, 0xf, true); v += __int_as_float(t);
    t = __builtin_amdgcn_update_dpp(0, __float_as_int(v), 0x142, 0xf, 0xf, true); v += __int_as_float(t);
    t = __builtin_amdgcn_update_dpp(0, __float_as_int(v), 0x143, 0xf, 0xf, true); v += __int_as_float(t);
    return v;
}
__device__ __forceinline__ int rdlane(int v, int l) { return __builtin_amdgcn_readlane(v, l); }
__device__ __forceinline__ u64 rdlane64(u64 v, int l) {
    unsigned lo = (unsigned)rdlane((int)(unsigned)v, l);
    unsigned hi = (unsigned)rdlane((int)(unsigned)(v >> 32), l);
    return ((u64)hi << 32) | lo;
}
__device__ __forceinline__ int div48(int j) { return ((j >> 4) * 21846) >> 16; }  // exact for j<3072

// ---------- sequential topo-sort: everything LDS-resident; background k2g ----------
__global__ __launch_bounds__(256) void topo_kernel(const float* __restrict__ elog_g,
                                                   const unsigned* __restrict__ keyenc_g,
                                                   const int* __restrict__ indeg_g,
                                                   const unsigned* __restrict__ eoff_g,
                                                   const unsigned short* __restrict__ edges_g,
                                                   float* __restrict__ gslog,
                                                   unsigned* __restrict__ gssel,
                                                   float* __restrict__ out) {
    __shared__ u64            s_node[NN + 8];          // hi=indeg (INF once selected), lo=keyenc
    __shared__ float          s_elog[NN];
    __shared__ unsigned       s_eoff[NN + 1];
    __shared__ unsigned short s_edges[EDGE_CAP + 128]; // +pad for clamped OOB-lane reads

    const int tid = threadIdx.x;

    // ---- cooperative staging by all 4 waves ----
    for (int x = tid; x < NN / 4; x += 256) {
        uint4 ke = ((const uint4*)keyenc_g)[x];
        uint4 dg = ((const uint4*)indeg_g)[x];
        s_node[4 * x + 0] = ((u64)dg.x << 32) | ke.x;
        s_node[4 * x + 1] = ((u64)dg.y << 32) | ke.y;
        s_node[4 * x + 2] = ((u64)dg.z << 32) | ke.z;
        s_node[4 * x + 3] = ((u64)dg.w << 32) | ke.w;
        ((float4*)s_elog)[x] = ((const float4*)elog_g)[x];
    }
    for (int x = tid; x <= NN; x += 256) s_eoff[x] = eoff_g[x];
    {
        unsigned total = eoff_g[NN];
        unsigned n32 = (total + 1) >> 1;
        unsigned cap32 = (EDGE_CAP + 128) / 2;
        if (n32 > cap32) n32 = cap32;
        for (unsigned x = tid; x < n32; x += 256)
            ((unsigned*)s_edges)[x] = ((const unsigned*)edges_g)[x];
    }
    __syncthreads();
    if (tid >= 64) return;              // wave 0 continues alone (no more barriers)

    const int lane = tid;
    const int base48 = lane * 48;       // lane OWNS nodes [48l, 48l+48)

    // ---- init: exact top-2 per group; S = sum over eligibles ----
    u64 key1 = 0ULL, key2 = 0ULL;
    float S;
    {
        unsigned b1 = 0u, b2 = 0u;
        int j1 = 0, j2i = 0;
        float ssl = 0.f;
        for (int i = 0; i < 48; ++i) {
            u64 nw = s_node[base48 + i];
            if ((unsigned)(nw >> 32) == 0u) {
                ssl += s_elog[base48 + i];
                unsigned e = (unsigned)nw;
                if (e > b1) { b2 = b1; j2i = j1; b1 = e; j1 = i; }
                else if (e > b2) { b2 = e; j2i = i; }
            }
        }
        if (b1) key1 = ((u64)b1 << 32) | (unsigned)(~(base48 + j1));
        if (b2) key2 = ((u64)b2 << 32) | (unsigned)(~(base48 + j2i));
        float tot = wsum_f32(ssl);
        S = __int_as_float(rdlane(__float_as_int(tot), 63));
    }

    // ---- initial tournament -> sel0; initial k2g; initial prefetch ----
    unsigned cur_sel;
    {
        unsigned vhi = (unsigned)(key1 >> 32);
        unsigned mx = (unsigned)rdlane((int)wmax_u32(vhi), 63);
        u64 ball = __ballot(vhi == mx);
        int gw = (int)__ffsll(ball) - 1;
        unsigned lo = (unsigned)rdlane((int)(unsigned)key1, gw);
        cur_sel = ~lo;
    }
    u64 k2g;
    {
        int gw = div48((int)cur_sel);
        unsigned re = (lane == gw) ? 0u : (unsigned)(key1 >> 32);
        unsigned mx = (unsigned)rdlane((int)wmax_u32(re), 63);
        u64 ball = __ballot(re == mx);
        int w = (int)__ffsll(ball) - 1;
        unsigned lo = (unsigned)rdlane((int)(unsigned)key1, w);
        u64 k2x = mx ? (((u64)mx << 32) | lo) : 0ULL;
        u64 k2b = rdlane64(key2, gw);
        k2g = k2x > k2b ? k2x : k2b;
    }
    unsigned e0 = s_eoff[cur_sel];
    unsigned e1 = s_eoff[cur_sel + 1];
    float elog_sel = s_elog[cur_sel];

    for (int t = 0; t < NN; ++t) {
        const int sel = (int)cur_sel;       // uniform
        const int g = div48(sel);

        // record (global fire-and-forget) + mark selected
        if (lane == 0) {
            gslog[t] = S;
            gssel[t] = (unsigned)sel;
            ((unsigned*)&s_node[sel])[1] = 0xFFFFFFFFu;
        }

        // substitution: winner group's new max = its exact 2nd (registers)
        bool isg = (lane == g);
        key1 = isg ? key2 : key1;
        key2 = isg ? 0ULL : key2;
        unsigned idx1 = ~(unsigned)rdlane((int)(unsigned)key1, g);
        u64 rn = s_node[g * 48 + (lane < 48 ? lane : 47)];   // group snapshot

        // ---- edge pass 1: one edge per lane (d<=64 virtually always) ----
        int d = (int)(e1 - e0);
        bool act = (lane < d);
        int j = (int)s_edges[e0 + (act ? lane : 0)];
        j = act ? j : 0;
        u64 nw = s_node[j];
        unsigned hi = (unsigned)(nw >> 32);
        ((unsigned*)&s_node[act ? j : NN])[1] = hi - 1u;     // predicated dummy slot
        u64 pend = (act && hi == 1u)
                 ? (((nw & 0xFFFFFFFFULL) << 32) | (unsigned)(~j)) : 0ULL;

        // ---- rescan apply (repairs key2 of lane g; BEFORE insertion updates) ----
        {
            int rl = g * 48 + lane;
            bool relig = (lane < 48) && ((unsigned)(rn >> 32) == 0u)
                       && (rl != sel) && (rl != (int)idx1);
            unsigned re = relig ? (unsigned)rn : 0u;
            unsigned rmx = (unsigned)rdlane((int)wmax_u32(re), 63);
            u64 rball = __ballot(re == rmx);
            int w0 = (int)__ffsll(rball) - 1;
            u64 nk2 = rmx ? (((u64)rmx << 32) | (unsigned)(~(g * 48 + w0))) : 0ULL;
            key2 = isg ? nk2 : key2;
        }

        // ---- merge insertions: owner key updates + global candidate + S ----
        u64 cand = 0ULL;
        u64 ib = __ballot(pend != 0ULL);
        while (ib) {
            int src = (int)__ffsll(ib) - 1; ib &= ib - 1;
            u64 kfull = rdlane64(pend, src);
            int j3 = (int)~(unsigned)kfull;
            bool own = (lane == div48(j3));
            bool gt1 = kfull > key1, gt2 = kfull > key2;
            u64 ok1 = key1;
            key1 = (own && gt1) ? kfull : key1;
            key2 = own ? (gt1 ? ok1 : (gt2 ? kfull : key2)) : key2;
            cand = kfull > cand ? kfull : cand;
            S += s_elog[j3];                      // uniform broadcast read
        }

        // rare slow path: column degree > 64
        if (d > 64) {
            for (int i2 = 64 + lane; ; i2 += 64) {
                u64 p2 = 0ULL;
                if (i2 < d) {
                    int jj = (int)s_edges[e0 + i2];
                    u64 nw2 = s_node[jj];
                    unsigned h2 = (unsigned)(nw2 >> 32);
                    ((unsigned*)&s_node[jj])[1] = h2 - 1u;
                    if (h2 == 1u)
                        p2 = ((nw2 & 0xFFFFFFFFULL) << 32) | (unsigned)(~jj);
                }
                u64 ib2 = __ballot(p2 != 0ULL);
                while (ib2) {
                    int src = (int)__ffsll(ib2) - 1; ib2 &= ib2 - 1;
                    u64 kfull = rdlane64(p2, src);
                    int j3 = (int)~(unsigned)kfull;
                    bool own = (lane == div48(j3));
                    bool gt1 = kfull > key1, gt2 = kfull > key2;
                    u64 ok1 = key1;
                    key1 = (own && gt1) ? kfull : key1;
                    key2 = own ? (gt1 ? ok1 : (gt2 ? kfull : key2)) : key2;
                    cand = kfull > cand ? kfull : cand;
                    S += s_elog[j3];
                }
                if (__ballot(i2 + 64 < d) == 0ULL) break;
            }
        }

        // ---- next winner: max(k2g, insertions) — NO tournament on the chain ----
        u64 wcand = k2g > cand ? k2g : cand;
        unsigned nsel = ~(unsigned)wcand;
        if (nsel >= NN) nsel = 0;                 // fires only at t == NN-1
        // prefetch next column offsets + elog
        e0 = s_eoff[nsel];
        e1 = s_eoff[nsel + 1];
        float elog_next = s_elog[nsel];

        // ---- background: k2g for next iteration ----
        {
            int gw2 = div48((int)nsel);
            unsigned re = (lane == gw2) ? 0u : (unsigned)(key1 >> 32);
            unsigned mx = (unsigned)rdlane((int)wmax_u32(re), 63);
            u64 ball = __ballot(re == mx);
            int w = (int)__ffsll(ball) - 1;
            unsigned lo = (unsigned)rdlane((int)(unsigned)key1, w);
            u64 k2x = mx ? (((u64)mx << 32) | lo) : 0ULL;
            u64 k2b = rdlane64(key2, gw2);
            k2g = k2x > k2b ? k2x : k2b;
        }

        // ---- S finalize (off-chain; consumed by next iter's record) ----
        S -= elog_sel;
        elog_sel = elog_next;
        cur_sel = nsel;
    }

    // ---- epilogue: all log_probs in parallel ----
    for (int i = lane; i < NN; i += 64) {
        unsigned si = gssel[i];
        float Si = gslog[i];
        out[si] = -logf((1.0f / s_elog[si]) * Si + 1e-10f);
    }
}

extern "C" void kernel_launch(void* const* d_in, const int* in_sizes, int n_in,
                              void* d_out, int out_size, void* d_ws, size_t ws_size,
                              hipStream_t stream) {
    const float* logits = (const float*)d_in[0];
    const float* adj    = (const float*)d_in[1];
    const float* unif   = (const float*)d_in[2];
    float* out = (float*)d_out;

    char* ws = (char*)d_ws;
    float*          rowsum = (float*)(ws + 0);          // 12,288 B
    unsigned*       colcnt = (unsigned*)(ws + 16384);   // 12,288 B
    unsigned*       eoff   = (unsigned*)(ws + 32768);   // 12,292 B
    unsigned short* edges  = (unsigned short*)(ws + 49152);  // 106,496 B
    float*          elog   = (float*)(ws + 157696);
    unsigned*       keyenc = (unsigned*)(ws + 169984);
    int*            indeg  = (int*)(ws + 182272);
    float*          gslog  = (float*)(ws + 194560);
    unsigned*       gssel  = (unsigned*)(ws + 206848);  // ends 219,136

    rowsum_kernel<<<NN, 256, 0, stream>>>(adj, rowsum);
    colcnt_kernel<<<NN / 256, 256, 0, stream>>>(adj, colcnt);
    scan_kernel<<<1, 64, 0, stream>>>(colcnt, eoff);
    fill_kernel<<<NN / 256, 256, 0, stream>>>(adj, eoff, edges);
    gumbel_kernel<<<NN / 256, 256, 0, stream>>>(logits, unif, rowsum, out,
                                                elog, keyenc, indeg);
    topo_kernel<<<1, 256, 0, stream>>>(elog, keyenc, indeg, eoff, edges,
                                       gslog, gssel, out);
}

// Round 12
// 1742.941 us; speedup vs baseline: 1.4861x; 1.4861x over previous
//
#include <hip/hip_runtime.h>
#include <math.h>

#define NN 3072
#define EPSG 1e-20f
#define EDGE_CAP 53248          // ~47.2K expected edges + margin
#define RCH 128                 // rows per chunk
#define NCH 24                  // chunks (24*128 = 3072)
typedef unsigned long long u64;

// ---------- prep 1: rowsum0[i] = sum_c adj[i][c] ----------
__global__ __launch_bounds__(256) void rowsum_kernel(const float* __restrict__ adj,
                                                     float* __restrict__ rowsum) {
    int row = blockIdx.x;
    const float* r = adj + (size_t)row * NN;
    float s = 0.f;
    for (int c = threadIdx.x; c < NN; c += 256) s += r[c];
#pragma unroll
    for (int off = 32; off > 0; off >>= 1) s += __shfl_down(s, off);
    __shared__ float ps[4];
    if ((threadIdx.x & 63) == 0) ps[threadIdx.x >> 6] = s;
    __syncthreads();
    if (threadIdx.x == 0) rowsum[row] = (ps[0] + ps[1]) + (ps[2] + ps[3]);
}

// ---------- prep 2a: per-chunk column counts (288 blocks, coalesced) ----------
__global__ __launch_bounds__(256) void cnt_kernel(const float* __restrict__ adj,
                                                  unsigned* __restrict__ cnt) {
    int c = blockIdx.x * 256 + threadIdx.x;
    const float* col = adj + (size_t)(blockIdx.y * RCH) * NN + c;
    unsigned n = 0;
#pragma unroll 4
    for (int i = 0; i < RCH; ++i)
        n += (col[(size_t)i * NN] != 0.0f) ? 1u : 0u;
    cnt[blockIdx.y * NN + c] = n;
}

// ---------- prep 2b: total per-column counts ----------
__global__ __launch_bounds__(256) void colsum_kernel(const unsigned* __restrict__ cnt,
                                                     unsigned* __restrict__ colcnt) {
    int c = blockIdx.x * 256 + threadIdx.x;
    unsigned n = 0;
    for (int by = 0; by < NCH; ++by) n += cnt[by * NN + c];
    colcnt[c] = n;
}

// ---------- prep 2c: exclusive scan of column counts (1 wave) ----------
__global__ __launch_bounds__(64) void scan_kernel(const unsigned* __restrict__ colcnt,
                                                  unsigned* __restrict__ eoff) {
    int lane = threadIdx.x;
    unsigned tot = 0;
    for (int k = 0; k < 48; ++k) tot += colcnt[lane * 48 + k];
    unsigned x = tot;
    for (int off = 1; off < 64; off <<= 1) {
        unsigned y = __shfl_up(x, off);
        if (lane >= off) x += y;
    }
    unsigned run = x - tot;
    for (int k = 0; k < 48; ++k) {
        unsigned c = colcnt[lane * 48 + k];
        eoff[lane * 48 + k] = run;
        run += c;
    }
    if (lane == 63) eoff[NN] = run;
}

// ---------- prep 2d: per-(chunk,column) start offsets ----------
__global__ __launch_bounds__(256) void choff_kernel(const unsigned* __restrict__ cnt,
                                                    const unsigned* __restrict__ eoff,
                                                    unsigned* __restrict__ choff) {
    int c = blockIdx.x * 256 + threadIdx.x;
    unsigned run = eoff[c];
    for (int by = 0; by < NCH; ++by) {
        choff[by * NN + c] = run;
        run += cnt[by * NN + c];
    }
}

// ---------- prep 2e: fill CSC edge lists (288 blocks; ascending row order) ----------
__global__ __launch_bounds__(256) void fill2_kernel(const float* __restrict__ adj,
                                                    const unsigned* __restrict__ choff,
                                                    unsigned short* __restrict__ edges) {
    int c = blockIdx.x * 256 + threadIdx.x;
    int r0 = blockIdx.y * RCH;
    unsigned off = choff[blockIdx.y * NN + c];
    const float* col = adj + (size_t)r0 * NN + c;
    for (int i = 0; i < RCH; ++i) {
        if (col[(size_t)i * NN] != 0.0f) {
            if (off < EDGE_CAP) edges[off] = (unsigned short)(r0 + i);
            ++off;
        }
    }
}

// monotonic order-preserving float->u32 map (never 0 for finite inputs)
__device__ __forceinline__ unsigned enc32(float v) {
    unsigned u = __float_as_uint(v);
    return (u & 0x80000000u) ? ~u : (u | 0x80000000u);
}

// ---------- prep 3: gumbel + derived per-node arrays ----------
__global__ __launch_bounds__(256) void gumbel_kernel(const float* __restrict__ logits,
                                                     const float* __restrict__ unif,
                                                     const float* __restrict__ rowsum,
                                                     float* __restrict__ out,
                                                     float* __restrict__ elog,
                                                     unsigned* __restrict__ keyenc,
                                                     int* __restrict__ indeg) {
    int j = blockIdx.x * 256 + threadIdx.x;
    float lg = logits[j];
    float u  = unif[j];
    float g  = lg + (-logf(-logf(u + EPSG) + EPSG));
    out[NN + j] = g;                 // gumbel_logits output
    elog[j] = expf(lg);
    keyenc[j] = enc32(g);
    indeg[j] = (int)rowsum[j];
}

// DPP wave64 max-reduce: result valid in lane 63
__device__ __forceinline__ unsigned wmax_u32(unsigned v) {
    unsigned t;
    t = (unsigned)__builtin_amdgcn_update_dpp(0, (int)v, 0x111, 0xf, 0xf, true); v = t > v ? t : v;
    t = (unsigned)__builtin_amdgcn_update_dpp(0, (int)v, 0x112, 0xf, 0xf, true); v = t > v ? t : v;
    t = (unsigned)__builtin_amdgcn_update_dpp(0, (int)v, 0x114, 0xf, 0xf, true); v = t > v ? t : v;
    t = (unsigned)__builtin_amdgcn_update_dpp(0, (int)v, 0x118, 0xf, 0xf, true); v = t > v ? t : v;
    t = (unsigned)__builtin_amdgcn_update_dpp(0, (int)v, 0x142, 0xf, 0xf, true); v = t > v ? t : v;
    t = (unsigned)__builtin_amdgcn_update_dpp(0, (int)v, 0x143, 0xf, 0xf, true); v = t > v ? t : v;
    return v;
}
__device__ __forceinline__ float wsum_f32(float v) {
    int t;
    t = __builtin_amdgcn_update_dpp(0, __float_as_int(v), 0x111, 0xf, 0xf, true); v += __int_as_float(t);
    t = __builtin_amdgcn_update_dpp(0, __float_as_int(v), 0x112, 0xf, 0xf, true); v += __int_as_float(t);
    t = __builtin_amdgcn_update_dpp(0, __float_as_int(v), 0x114, 0xf, 0xf, true); v += __int_as_float(t);
    t = __builtin_amdgcn_update_dpp(0, __float_as_int(v), 0x118, 0xf, 0xf, true); v += __int_as_float(t);
    t = __builtin_amdgcn_update_dpp(0, __float_as_int(v), 0x142, 0xf, 0xf, true); v += __int_as_float(t);
    t = __builtin_amdgcn_update_dpp(0, __float_as_int(v), 0x143, 0xf, 0xf, true); v += __int_as_float(t);
    return v;
}
__device__ __forceinline__ int rdlane(int v, int l) { return __builtin_amdgcn_readlane(v, l); }
__device__ __forceinline__ u64 rdlane64(u64 v, int l) {
    unsigned lo = (unsigned)rdlane((int)(unsigned)v, l);
    unsigned hi = (unsigned)rdlane((int)(unsigned)(v >> 32), l);
    return ((u64)hi << 32) | lo;
}
__device__ __forceinline__ int div48(int j) { return ((j >> 4) * 21846) >> 16; }  // exact for j<3072

// ---------- sequential topo-sort: fused node4 state, background k2g ----------
__global__ __launch_bounds__(256) void topo_kernel(const float* __restrict__ elog_g,
                                                   const unsigned* __restrict__ keyenc_g,
                                                   const int* __restrict__ indeg_g,
                                                   const unsigned* __restrict__ eoff_g,
                                                   const unsigned short* __restrict__ edges_g,
                                                   float* __restrict__ gslog,
                                                   unsigned* __restrict__ gssel,
                                                   float* __restrict__ out) {
    // s_node4[j] = {keyenc, indeg (0xFFFFFFFF once selected), elog bits, eoff | d<<20}
    __shared__ uint4          s_node4[NN + 4];          // +4 dummy slots
    __shared__ unsigned short s_edges[EDGE_CAP + 128];  // +pad for clamped reads

    const int tid = threadIdx.x;

    // ---- cooperative staging by all 4 waves ----
    for (int j = tid; j < NN; j += 256) {
        unsigned e0 = eoff_g[j];
        unsigned e1 = eoff_g[j + 1];
        uint4 w;
        w.x = keyenc_g[j];
        w.y = (unsigned)indeg_g[j];
        w.z = __float_as_uint(elog_g[j]);
        w.w = e0 | ((e1 - e0) << 20);
        s_node4[j] = w;
    }
    {
        unsigned total = eoff_g[NN];
        unsigned n32 = (total + 1) >> 1;
        unsigned cap32 = (EDGE_CAP + 128) / 2;
        if (n32 > cap32) n32 = cap32;
        for (unsigned x = tid; x < n32; x += 256)
            ((unsigned*)s_edges)[x] = ((const unsigned*)edges_g)[x];
    }
    __syncthreads();
    if (tid >= 64) return;              // wave 0 continues alone

    const int lane = tid;
    const int base48 = lane * 48;       // lane OWNS nodes [48l, 48l+48)

    // ---- init: exact top-2 per group; S over eligibles ----
    u64 key1 = 0ULL, key2 = 0ULL;
    float S;
    {
        unsigned b1 = 0u, b2 = 0u;
        int j1 = 0, j2i = 0;
        float ssl = 0.f;
        for (int i = 0; i < 48; ++i) {
            uint4 nw = s_node4[base48 + i];
            if (nw.y == 0u) {
                ssl += __uint_as_float(nw.z);
                if (nw.x > b1) { b2 = b1; j2i = j1; b1 = nw.x; j1 = i; }
                else if (nw.x > b2) { b2 = nw.x; j2i = i; }
            }
        }
        if (b1) key1 = ((u64)b1 << 32) | (unsigned)(~(base48 + j1));
        if (b2) key2 = ((u64)b2 << 32) | (unsigned)(~(base48 + j2i));
        float tot = wsum_f32(ssl);
        S = __int_as_float(rdlane(__float_as_int(tot), 63));
    }

    // ---- initial tournament -> sel0 ----
    unsigned cur_sel;
    {
        unsigned vhi = (unsigned)(key1 >> 32);
        unsigned mx = (unsigned)rdlane((int)wmax_u32(vhi), 63);
        u64 ball = __ballot(vhi == mx);
        int gw = (int)__ffsll(ball) - 1;
        unsigned lo = (unsigned)rdlane((int)(unsigned)key1, gw);
        cur_sel = ~lo;
    }
    // initial k2g
    u64 k2g;
    {
        int gw = div48((int)cur_sel);
        unsigned re = (lane == gw) ? 0u : (unsigned)(key1 >> 32);
        unsigned mx = (unsigned)rdlane((int)wmax_u32(re), 63);
        u64 ball = __ballot(re == mx);
        int w = (int)__ffsll(ball) - 1;
        unsigned lo = (unsigned)rdlane((int)(unsigned)key1, w);
        u64 k2x = mx ? (((u64)mx << 32) | lo) : 0ULL;
        u64 k2b = rdlane64(key2, gw);
        k2g = k2x > k2b ? k2x : k2b;
    }
    // initial prefetch of sel's metadata
    unsigned e0, dd;
    float elog_sel;
    {
        uint4 nwsel = s_node4[cur_sel];
        elog_sel = __uint_as_float(nwsel.z);
        e0 = nwsel.w & 0xFFFFFu;
        dd = nwsel.w >> 20;
    }

    for (int t = 0; t < NN; ++t) {
        const int sel = (int)cur_sel;       // uniform
        const int g = div48(sel);

        // ---- edge pass: one edge per lane (d<=64 virtually always) ----
        int d = (int)dd;
        bool act = (lane < d);
        int j = (int)s_edges[e0 + (act ? lane : 0)];
        j = act ? j : 0;
        uint4 nw = s_node4[j];                       // one b128 read: key+indeg+elog
        unsigned hi = nw.y;
        ((unsigned*)&s_node4[act ? j : NN])[1] = hi - 1u;   // predicated decrement
        bool ins = act && (hi == 1u);
        u64 pend = ins ? (((u64)nw.x << 32) | (unsigned)(~j)) : 0ULL;
        float pelog = __uint_as_float(nw.z);

        // record (global fire-and-forget) + mark selected
        if (lane == 0) {
            gslog[t] = S;
            gssel[t] = (unsigned)sel;
            ((unsigned*)&s_node4[sel])[1] = 0xFFFFFFFFu;
        }

        // substitution: winner group's new max = its exact 2nd (registers)
        bool isg = (lane == g);
        key1 = isg ? key2 : key1;
        key2 = isg ? 0ULL : key2;
        unsigned idx1 = ~(unsigned)rdlane((int)(unsigned)key1, g);
        // group-g snapshot for rescan (b64: keyenc+indeg), pre-decrement not guaranteed
        u64 rn = *(const u64*)&s_node4[g * 48 + (lane < 48 ? lane : 47)];

        // ---- rescan apply (repairs key2 of lane g; BEFORE insertion updates) ----
        {
            int rl = g * 48 + lane;
            bool relig = (lane < 48) && ((unsigned)(rn >> 32) == 0u)
                       && (rl != sel) && (rl != (int)idx1);
            unsigned re = relig ? (unsigned)rn : 0u;
            unsigned rmx = (unsigned)rdlane((int)wmax_u32(re), 63);
            u64 rball = __ballot(re == rmx);
            int w0 = (int)__ffsll(rball) - 1;
            u64 nk2 = rmx ? (((u64)rmx << 32) | (unsigned)(~(g * 48 + w0))) : 0ULL;
            key2 = isg ? nk2 : key2;
        }

        // ---- merge insertions: owner key updates + global candidate + S ----
        u64 cand = 0ULL;
        u64 ib = __ballot(pend != 0ULL);
        while (ib) {
            int src = (int)__ffsll(ib) - 1; ib &= ib - 1;
            u64 kfull = rdlane64(pend, src);
            float el = __int_as_float(rdlane(__float_as_int(pelog), src));
            int j3 = (int)~(unsigned)kfull;
            bool own = (lane == div48(j3));
            bool gt1 = kfull > key1, gt2 = kfull > key2;
            u64 ok1 = key1;
            key1 = (own && gt1) ? kfull : key1;
            key2 = own ? (gt1 ? ok1 : (gt2 ? kfull : key2)) : key2;
            cand = kfull > cand ? kfull : cand;
            S += el;
        }

        // rare slow path: column degree > 64
        if (d > 64) {
            for (int i2 = 64 + lane; ; i2 += 64) {
                u64 p2 = 0ULL;
                float p2el = 0.f;
                if (i2 < d) {
                    int jj = (int)s_edges[e0 + i2];
                    uint4 nw2 = s_node4[jj];
                    ((unsigned*)&s_node4[jj])[1] = nw2.y - 1u;
                    if (nw2.y == 1u) {
                        p2 = ((u64)nw2.x << 32) | (unsigned)(~jj);
                        p2el = __uint_as_float(nw2.z);
                    }
                }
                u64 ib2 = __ballot(p2 != 0ULL);
                while (ib2) {
                    int src = (int)__ffsll(ib2) - 1; ib2 &= ib2 - 1;
                    u64 kfull = rdlane64(p2, src);
                    float el = __int_as_float(rdlane(__float_as_int(p2el), src));
                    int j3 = (int)~(unsigned)kfull;
                    bool own = (lane == div48(j3));
                    bool gt1 = kfull > key1, gt2 = kfull > key2;
                    u64 ok1 = key1;
                    key1 = (own && gt1) ? kfull : key1;
                    key2 = own ? (gt1 ? ok1 : (gt2 ? kfull : key2)) : key2;
                    cand = kfull > cand ? kfull : cand;
                    S += el;
                }
                if (__ballot(i2 + 64 < d) == 0ULL) break;
            }
        }

        // ---- next winner: max(k2g, insertions) — no tournament on the chain ----
        u64 wcand = k2g > cand ? k2g : cand;
        unsigned nsel = ~(unsigned)wcand;
        if (nsel >= NN) nsel = 0;                 // fires only at t == NN-1

        // prefetch next sel's metadata (z,w immutable -> race-free)
        uint4 nwn = s_node4[nsel];
        float elog_next = __uint_as_float(nwn.z);
        unsigned e0n = nwn.w & 0xFFFFFu;
        unsigned ddn = nwn.w >> 20;

        // ---- background: k2g for next iteration ----
        {
            int gw2 = div48((int)nsel);
            unsigned re = (lane == gw2) ? 0u : (unsigned)(key1 >> 32);
            unsigned mx = (unsigned)rdlane((int)wmax_u32(re), 63);
            u64 ball = __ballot(re == mx);
            int w = (int)__ffsll(ball) - 1;
            unsigned lo = (unsigned)rdlane((int)(unsigned)key1, w);
            u64 k2x = mx ? (((u64)mx << 32) | lo) : 0ULL;
            u64 k2b = rdlane64(key2, gw2);
            k2g = k2x > k2b ? k2x : k2b;
        }

        // ---- S finalize (off-chain) ----
        S -= elog_sel;
        elog_sel = elog_next;
        e0 = e0n;
        dd = ddn;
        cur_sel = nsel;
    }

    // ---- epilogue: all log_probs in parallel ----
    for (int i = lane; i < NN; i += 64) {
        unsigned si = gssel[i];
        float Si = gslog[i];
        float el = __uint_as_float(s_node4[si].z);
        out[si] = -logf((1.0f / el) * Si + 1e-10f);
    }
}

extern "C" void kernel_launch(void* const* d_in, const int* in_sizes, int n_in,
                              void* d_out, int out_size, void* d_ws, size_t ws_size,
                              hipStream_t stream) {
    const float* logits = (const float*)d_in[0];
    const float* adj    = (const float*)d_in[1];
    const float* unif   = (const float*)d_in[2];
    float* out = (float*)d_out;

    char* ws = (char*)d_ws;
    float*          rowsum = (float*)(ws + 0);                    // 12,288
    unsigned*       cnt    = (unsigned*)(ws + 16384);             // 294,912
    unsigned*       colcnt = (unsigned*)(ws + 311296);            // 12,288
    unsigned*       eoff   = (unsigned*)(ws + 323584);            // 12,292
    unsigned*       choff  = (unsigned*)(ws + 339968);            // 294,912
    unsigned short* edges  = (unsigned short*)(ws + 634880);      // 106,496
    float*          elog   = (float*)(ws + 741376);               // 12,288
    unsigned*       keyenc = (unsigned*)(ws + 753664);            // 12,288
    int*            indeg  = (int*)(ws + 765952);                 // 12,288
    float*          gslog  = (float*)(ws + 778240);               // 12,288
    unsigned*       gssel  = (unsigned*)(ws + 790528);            // ends 802,816

    rowsum_kernel<<<NN, 256, 0, stream>>>(adj, rowsum);
    cnt_kernel<<<dim3(NN / 256, NCH), 256, 0, stream>>>(adj, cnt);
    colsum_kernel<<<NN / 256, 256, 0, stream>>>(cnt, colcnt);
    scan_kernel<<<1, 64, 0, stream>>>(colcnt, eoff);
    choff_kernel<<<NN / 256, 256, 0, stream>>>(cnt, eoff, choff);
    fill2_kernel<<<dim3(NN / 256, NCH), 256, 0, stream>>>(adj, choff, edges);
    gumbel_kernel<<<NN / 256, 256, 0, stream>>>(logits, unif, rowsum, out,
                                                elog, keyenc, indeg);
    topo_kernel<<<1, 256, 0, stream>>>(elog, keyenc, indeg, eoff, edges,
                                       gslog, gssel, out);
}